// Round 1
// baseline (4222.724 us; speedup 1.0000x reference)
//
#include <hip/hip_runtime.h>

#define SEQ   1024
#define BATCH 512
#define IN_DIM 128
#define HID   128
#define GCOLS 512   // 4 gates * HID

// ---------------------------------------------------------------------------
// Kernel 1: Z[r][j] = X[r][:] @ Wgate[0:128][col] + bias   (input half only)
// rows = chunk*BATCH, each WG does 32 rows x 512 cols, thread = 4 rows x 16 cols
// ---------------------------------------------------------------------------
__global__ __launch_bounds__(256) void qlstm_xgemm(
    const float* __restrict__ X,     // [nrows, 128]
    const float* __restrict__ Wf, const float* __restrict__ bf,
    const float* __restrict__ Wi, const float* __restrict__ bi,
    const float* __restrict__ Wg, const float* __restrict__ bg,
    const float* __restrict__ Wo, const float* __restrict__ bo,
    float* __restrict__ Z, int nrows)
{
    __shared__ float xt[32][128];
    const int tid = threadIdx.x;
    const int rowbase = blockIdx.x * 32;

    // stage X tile (32 rows x 128) -> LDS, float4 coalesced
    const float4* Xv = (const float4*)(X + (size_t)rowbase * IN_DIM);
    float4* xtv = (float4*)&xt[0][0];
    #pragma unroll
    for (int i = 0; i < 4; ++i) xtv[tid + i * 256] = Xv[tid + i * 256];
    __syncthreads();

    const int tx = tid & 31;          // col group: global cols tx*16 .. tx*16+15
    const int ty = tid >> 5;          // row group: rows ty*4 .. ty*4+3
    const int g  = tx >> 3;           // gate id 0..3
    const float* Wsel = (g == 0) ? Wf : (g == 1) ? Wi : (g == 2) ? Wg : Wo;
    const float* bsel = (g == 0) ? bf : (g == 1) ? bi : (g == 2) ? bg : bo;
    const int gcol0 = (tx & 7) * 16;  // col within gate

    float acc[4][16];
    #pragma unroll
    for (int r = 0; r < 4; ++r)
        #pragma unroll
        for (int c = 0; c < 16; ++c) acc[r][c] = 0.f;

    #pragma unroll 2
    for (int k = 0; k < 128; ++k) {
        const float* wp = Wsel + k * 128 + gcol0;
        float4 wa = *(const float4*)(wp);
        float4 wb = *(const float4*)(wp + 4);
        float4 wc = *(const float4*)(wp + 8);
        float4 wd = *(const float4*)(wp + 12);
        #pragma unroll
        for (int r = 0; r < 4; ++r) {
            float xv = xt[ty * 4 + r][k];
            acc[r][0]  = fmaf(xv, wa.x, acc[r][0]);
            acc[r][1]  = fmaf(xv, wa.y, acc[r][1]);
            acc[r][2]  = fmaf(xv, wa.z, acc[r][2]);
            acc[r][3]  = fmaf(xv, wa.w, acc[r][3]);
            acc[r][4]  = fmaf(xv, wb.x, acc[r][4]);
            acc[r][5]  = fmaf(xv, wb.y, acc[r][5]);
            acc[r][6]  = fmaf(xv, wb.z, acc[r][6]);
            acc[r][7]  = fmaf(xv, wb.w, acc[r][7]);
            acc[r][8]  = fmaf(xv, wc.x, acc[r][8]);
            acc[r][9]  = fmaf(xv, wc.y, acc[r][9]);
            acc[r][10] = fmaf(xv, wc.z, acc[r][10]);
            acc[r][11] = fmaf(xv, wc.w, acc[r][11]);
            acc[r][12] = fmaf(xv, wd.x, acc[r][12]);
            acc[r][13] = fmaf(xv, wd.y, acc[r][13]);
            acc[r][14] = fmaf(xv, wd.z, acc[r][14]);
            acc[r][15] = fmaf(xv, wd.w, acc[r][15]);
        }
    }

    float bb[16];
    #pragma unroll
    for (int c = 0; c < 16; ++c) bb[c] = bsel[gcol0 + c];

    #pragma unroll
    for (int r = 0; r < 4; ++r) {
        float* zp = Z + ((size_t)(rowbase + ty * 4 + r)) * GCOLS + tx * 16;
        #pragma unroll
        for (int c = 0; c < 16; c += 4) {
            float4 v;
            v.x = acc[r][c + 0] + bb[c + 0];
            v.y = acc[r][c + 1] + bb[c + 1];
            v.z = acc[r][c + 2] + bb[c + 2];
            v.w = acc[r][c + 3] + bb[c + 3];
            *(float4*)(zp + c) = v;
        }
    }
}

// ---------------------------------------------------------------------------
// Kernel 2: persistent recurrent kernel. 256 WGs x 512 threads; each WG owns
// 2 batch rows for the whole chunk. Thread j holds Wh column j (gate j>>7,
// col j&127) in registers. h,c live in LDS; state handed off via ws between
// chunk launches.
// ---------------------------------------------------------------------------
__global__ __launch_bounds__(512, 2) void qlstm_rec(
    const float* __restrict__ Z,   // [chunk, BATCH, 512]
    const float* __restrict__ Wf, const float* __restrict__ Wi,
    const float* __restrict__ Wg, const float* __restrict__ Wo,
    float* __restrict__ out,       // [SEQ, BATCH, HID] base
    float* __restrict__ hstate,    // [BATCH, HID]
    float* __restrict__ cstate,    // [BATCH, HID]
    int t0, int chunk)
{
    __shared__ float h_lds[2][128];
    __shared__ float c_lds[2][128];
    __shared__ float gact[4][2][128];
    __shared__ float scanT[2];

    const int tid  = threadIdx.x;
    const int gate = tid >> 7;
    const int col  = tid & 127;
    const int lane = tid & 63;
    const int wid  = tid >> 6;
    const int row0 = blockIdx.x * 2;

    const float* Wsel = (gate == 0) ? Wf : (gate == 1) ? Wi : (gate == 2) ? Wg : Wo;

    // recurrent weight column -> registers (static indices, stays in VGPRs)
    float wreg[128];
    #pragma unroll
    for (int k = 0; k < 128; ++k) wreg[k] = Wsel[(128 + k) * 128 + col];

    if (tid < 256) {
        int r = tid >> 7, c = tid & 127;
        h_lds[r][c] = hstate[(row0 + r) * 128 + c];
        c_lds[r][c] = cstate[(row0 + r) * 128 + c];
    }
    __syncthreads();

    for (int t = 0; t < chunk; ++t) {
        const float* Zt = Z + ((size_t)t * BATCH + row0) * GCOLS + tid;
        float acc0 = Zt[0];
        float acc1 = Zt[GCOLS];
        #pragma unroll
        for (int k4 = 0; k4 < 32; ++k4) {
            float4 h0 = *(const float4*)&h_lds[0][k4 * 4];
            float4 h1 = *(const float4*)&h_lds[1][k4 * 4];
            acc0 = fmaf(h0.x, wreg[4 * k4 + 0], acc0);
            acc0 = fmaf(h0.y, wreg[4 * k4 + 1], acc0);
            acc0 = fmaf(h0.z, wreg[4 * k4 + 2], acc0);
            acc0 = fmaf(h0.w, wreg[4 * k4 + 3], acc0);
            acc1 = fmaf(h1.x, wreg[4 * k4 + 0], acc1);
            acc1 = fmaf(h1.y, wreg[4 * k4 + 1], acc1);
            acc1 = fmaf(h1.z, wreg[4 * k4 + 2], acc1);
            acc1 = fmaf(h1.w, wreg[4 * k4 + 3], acc1);
        }

        float v0, v1;
        if (gate == 0) {
            // inclusive cumprod of cos across 128 cols (2 waves)
            float p0 = cosf(acc0), p1 = cosf(acc1);
            #pragma unroll
            for (int d = 1; d < 64; d <<= 1) {
                float q0 = __shfl_up(p0, d);
                float q1 = __shfl_up(p1, d);
                if (lane >= d) { p0 *= q0; p1 *= q1; }
            }
            v0 = p0; v1 = p1;
        } else if (gate == 1) {
            v0 = (cosf(acc0) + 1.f) * 0.5f;
            v1 = (cosf(acc1) + 1.f) * 0.5f;
        } else if (gate == 2) {
            v0 = tanhf(acc0);
            v1 = tanhf(acc1);
        } else {
            v0 = 1.f / (1.f + expf(-acc0));
            v1 = 1.f / (1.f + expf(-acc1));
        }
        if (wid == 0 && lane == 63) { scanT[0] = v0; scanT[1] = v1; }
        __syncthreads();                                    // S1
        if (gate == 0) {
            if (wid == 1) { v0 *= scanT[0]; v1 *= scanT[1]; }
            v0 = (v0 + 1.f) * 0.5f;
            v1 = (v1 + 1.f) * 0.5f;
        }
        gact[gate][0][col] = v0;
        gact[gate][1][col] = v1;
        __syncthreads();                                    // S2

        if (tid < 256) {
            int r = tid >> 7, c = tid & 127;
            float f = gact[0][r][c];
            float i = gact[1][r][c];
            float g = gact[2][r][c];
            float o = gact[3][r][c];
            float cn = fmaf(f, c_lds[r][c], i * g);
            float hn = o * tanhf(cn);
            c_lds[r][c] = cn;
            h_lds[r][c] = hn;
            out[((size_t)(t0 + t) * BATCH + row0 + r) * HID + c] = hn;
        }
        __syncthreads();                                    // S3
    }

    if (tid < 256) {
        int r = tid >> 7, c = tid & 127;
        hstate[(row0 + r) * 128 + c] = h_lds[r][c];
        cstate[(row0 + r) * 128 + c] = c_lds[r][c];
    }
}

// ---------------------------------------------------------------------------
extern "C" void kernel_launch(void* const* d_in, const int* in_sizes, int n_in,
                              void* d_out, int out_size, void* d_ws, size_t ws_size,
                              hipStream_t stream) {
    const float* X  = (const float*)d_in[0];
    const float* Wf = (const float*)d_in[1];
    const float* bf = (const float*)d_in[2];
    const float* Wi = (const float*)d_in[3];
    const float* bi = (const float*)d_in[4];
    const float* Wg = (const float*)d_in[5];
    const float* bg = (const float*)d_in[6];
    const float* Wo = (const float*)d_in[7];
    const float* bo = (const float*)d_in[8];
    float* out = (float*)d_out;

    char* ws = (char*)d_ws;
    const size_t state_bytes = (size_t)BATCH * HID * sizeof(float);   // 256 KB each
    float* hstate = (float*)ws;
    float* cstate = (float*)(ws + state_bytes);
    float* Zbuf   = (float*)(ws + 2 * state_bytes);

    const size_t z_step_bytes = (size_t)BATCH * GCOLS * sizeof(float); // 1 MB / step
    size_t zcap = (ws_size > 2 * state_bytes) ? (ws_size - 2 * state_bytes) : 0;
    int Tc = (int)(zcap / z_step_bytes);
    if (Tc > SEQ) Tc = SEQ;
    if (Tc < 1)   Tc = 1;

    hipMemsetAsync(hstate, 0, 2 * state_bytes, stream);

    for (int t0 = 0; t0 < SEQ; t0 += Tc) {
        int chunk = (SEQ - t0 < Tc) ? (SEQ - t0) : Tc;
        int nrows = chunk * BATCH;
        qlstm_xgemm<<<nrows / 32, 256, 0, stream>>>(
            X + (size_t)t0 * BATCH * IN_DIM,
            Wf, bf, Wi, bi, Wg, bg, Wo, bo, Zbuf, nrows);
        qlstm_rec<<<BATCH / 2, 512, 0, stream>>>(
            Zbuf, Wf, Wi, Wg, Wo, out, hstate, cstate, t0, chunk);
    }

    // final hx, cx appended after outputs (h then c, contiguous in ws)
    hipMemcpyAsync(out + (size_t)SEQ * BATCH * HID, hstate, 2 * state_bytes,
                   hipMemcpyDeviceToDevice, stream);
}

// Round 2
// 1664.100 us; speedup vs baseline: 2.5375x; 2.5375x over previous
//
#include <hip/hip_runtime.h>

#define SEQ   1024
#define BATCH 512
#define HID   128

typedef __attribute__((ext_vector_type(8))) short  short8v;
typedef __attribute__((ext_vector_type(4))) float  float4v;

__device__ __forceinline__ unsigned short f2bf(float f) {
    union { float f; unsigned u; } v; v.f = f;
    return (unsigned short)((v.u + 0x7fffu + ((v.u >> 16) & 1u)) >> 16);
}
__device__ __forceinline__ float fast_cos(float x) {
    return __builtin_amdgcn_cosf(x * 0.15915494309189535f);   // v_cos takes revolutions
}
__device__ __forceinline__ float fast_sigmoid(float x) {
    return __builtin_amdgcn_rcpf(1.0f + __builtin_amdgcn_exp2f(-1.4426950408889634f * x));
}
__device__ __forceinline__ float fast_tanh(float x) {
    return 1.0f - 2.0f * __builtin_amdgcn_rcpf(1.0f + __builtin_amdgcn_exp2f(2.8853900817779268f * x));
}

// raw barrier: no vmcnt drain (keeps x-prefetch in flight), explicit LDS publish
#define BAR() do { asm volatile("s_waitcnt lgkmcnt(0)" ::: "memory");  \
                   __builtin_amdgcn_s_barrier();                       \
                   __builtin_amdgcn_sched_barrier(0); } while (0)

// 256 WGs x 512 threads; WG owns batch rows {2b, 2b+1} for all 1024 steps.
// Per step: preact[2][512] = bias + [x,h]@W via mfma_16x16x32_bf16,
// A(weights) persistent in VGPRs, B = x (reg-prefetched) / h (LDS bf16).
__global__ __launch_bounds__(512, 2) void qlstm_fused(
    const float* __restrict__ X,
    const float* __restrict__ Wf, const float* __restrict__ bfp,
    const float* __restrict__ Wi, const float* __restrict__ bip,
    const float* __restrict__ Wg, const float* __restrict__ bgp,
    const float* __restrict__ Wo, const float* __restrict__ bop,
    float* __restrict__ out)
{
    __shared__ float preact[2][512];
    __shared__ float gact[4][2][128];
    __shared__ alignas(16) unsigned short h_bf[2][128];
    __shared__ float scanT[2];

    const int tid  = threadIdx.x;
    const int lane = tid & 63;
    const int wid  = tid >> 6;       // wave 0..7
    const int l15  = lane & 15;      // MFMA: A-row / D-col(batch slot)
    const int kg   = lane >> 4;      // MFMA: k-group 0..3
    const int row0 = blockIdx.x * 2;
    const int nn   = (l15 < 2) ? l15 : 1;   // clamp garbage lanes to row 1
    const bool act = (l15 < 2);

    // wave -> gate is uniform: cols [wid*64, wid*64+64)
    const int g = wid >> 1;
    const float* Wsel = (g == 0) ? Wf : (g == 1) ? Wi : (g == 2) ? Wg : Wo;
    const float* bsel = (g == 0) ? bfp : (g == 1) ? bip : (g == 2) ? bgp : bop;
    const int colbase = (wid & 1) * 64;

    // ---- persistent A fragments: W[k][col] (k 0..127 = x-part, 128..255 = h-part)
    short8v aw[4][8];            // [mtile][kstep] : 128 VGPRs
    float4v bias4[4];
    #pragma unroll
    for (int mt = 0; mt < 4; ++mt) {
        const int col = colbase + mt * 16 + l15;
        #pragma unroll
        for (int ks = 0; ks < 8; ++ks) {
            const int k0 = ks * 32 + kg * 8;
            short8v a;
            #pragma unroll
            for (int j = 0; j < 8; ++j)
                a[j] = (short)f2bf(Wsel[(size_t)(k0 + j) * HID + col]);
            aw[mt][ks] = a;
        }
        #pragma unroll
        for (int r = 0; r < 4; ++r)
            bias4[mt][r] = bsel[colbase + mt * 16 + kg * 4 + r];
    }

    if (tid < 256) h_bf[tid >> 7][tid & 127] = 0;

    // prefetch x[0]
    float4v xpre[4][2];
    {
        const float* xb = X + ((size_t)row0 + nn) * HID;
        #pragma unroll
        for (int ks = 0; ks < 4; ++ks) {
            xpre[ks][0] = *(const float4v*)(xb + ks * 32 + kg * 8);
            xpre[ks][1] = *(const float4v*)(xb + ks * 32 + kg * 8 + 4);
        }
    }

    float c_reg = 0.f, h_last = 0.f;
    BAR();

    for (int t = 0; t < SEQ; ++t) {
        // ---- Phase A: build B-frags, MFMA ----
        short8v bx[4];
        #pragma unroll
        for (int ks = 0; ks < 4; ++ks) {
            short8v b;
            #pragma unroll
            for (int j = 0; j < 4; ++j) {
                b[j]     = (short)f2bf(xpre[ks][0][j]);
                b[4 + j] = (short)f2bf(xpre[ks][1][j]);
            }
            bx[ks] = b;
        }
        // issue next-step x prefetch (flies across the whole step; raw barriers don't drain vmcnt)
        {
            const int tn = (t + 1 < SEQ) ? (t + 1) : (SEQ - 1);
            const float* xb = X + ((size_t)tn * BATCH + row0 + nn) * HID;
            #pragma unroll
            for (int ks = 0; ks < 4; ++ks) {
                xpre[ks][0] = *(const float4v*)(xb + ks * 32 + kg * 8);
                xpre[ks][1] = *(const float4v*)(xb + ks * 32 + kg * 8 + 4);
            }
        }
        short8v bh[4];
        #pragma unroll
        for (int ks = 0; ks < 4; ++ks)
            bh[ks] = *(const short8v*)&h_bf[nn][ks * 32 + kg * 8];

        float4v accv[4];
        #pragma unroll
        for (int mt = 0; mt < 4; ++mt) accv[mt] = bias4[mt];
        #pragma unroll
        for (int ks = 0; ks < 4; ++ks)
            #pragma unroll
            for (int mt = 0; mt < 4; ++mt)
                accv[mt] = __builtin_amdgcn_mfma_f32_16x16x32_bf16(aw[mt][ks], bx[ks], accv[mt], 0, 0, 0);
        #pragma unroll
        for (int ks = 0; ks < 4; ++ks)
            #pragma unroll
            for (int mt = 0; mt < 4; ++mt)
                accv[mt] = __builtin_amdgcn_mfma_f32_16x16x32_bf16(aw[mt][4 + ks], bh[ks], accv[mt], 0, 0, 0);

        // ---- Phase B: publish preacts (lanes with l15<2 hold real columns) ----
        if (act) {
            #pragma unroll
            for (int mt = 0; mt < 4; ++mt)
                *(float4v*)&preact[l15][wid * 64 + mt * 16 + kg * 4] = accv[mt];
        }
        BAR();  // S1

        // ---- Phase C: activations (thread tid <-> gate col m=tid, both rows) ----
        const int gate = tid >> 7;
        const int col  = tid & 127;
        const float a0 = preact[0][tid];
        const float a1 = preact[1][tid];
        float v0, v1;
        if (gate == 0) {
            float p0 = fast_cos(a0), p1 = fast_cos(a1);
            #pragma unroll
            for (int d = 1; d < 64; d <<= 1) {     // inclusive cumprod scan
                float q0 = __shfl_up(p0, d);
                float q1 = __shfl_up(p1, d);
                if (lane >= d) { p0 *= q0; p1 *= q1; }
            }
            if (wid == 0 && lane == 63) { scanT[0] = p0; scanT[1] = p1; }
            v0 = p0; v1 = p1;
        } else if (gate == 1) {
            v0 = (fast_cos(a0) + 1.f) * 0.5f;
            v1 = (fast_cos(a1) + 1.f) * 0.5f;
        } else if (gate == 2) {
            v0 = fast_tanh(a0);
            v1 = fast_tanh(a1);
        } else {
            v0 = fast_sigmoid(a0);
            v1 = fast_sigmoid(a1);
        }
        BAR();  // S2 (scanT handoff wave0 -> wave1)
        if (gate == 0) {
            if (wid == 1) { v0 *= scanT[0]; v1 *= scanT[1]; }
            v0 = (v0 + 1.f) * 0.5f;
            v1 = (v1 + 1.f) * 0.5f;
        }
        gact[gate][0][col] = v0;
        gact[gate][1][col] = v1;
        BAR();  // S3

        // ---- Phase D: state update (threads < 256 own (row r, col c)) ----
        if (tid < 256) {
            const int r = tid >> 7, c = tid & 127;
            const float f  = gact[0][r][c];
            const float i  = gact[1][r][c];
            const float gg = gact[2][r][c];
            const float o  = gact[3][r][c];
            const float cn = fmaf(f, c_reg, i * gg);
            const float hn = o * fast_tanh(cn);
            c_reg = cn; h_last = hn;
            h_bf[r][c] = f2bf(hn);
            out[((size_t)t * BATCH + row0 + r) * HID + c] = hn;
        }
        BAR();  // S4 (h_bf ready for next step's B-frags)
    }

    // final hx, cx appended after outputs
    if (tid < 256) {
        const int r = tid >> 7, c = tid & 127;
        const size_t base = (size_t)SEQ * BATCH * HID;
        out[base + (size_t)(row0 + r) * HID + c] = h_last;
        out[base + (size_t)BATCH * HID + (size_t)(row0 + r) * HID + c] = c_reg;
    }
}

extern "C" void kernel_launch(void* const* d_in, const int* in_sizes, int n_in,
                              void* d_out, int out_size, void* d_ws, size_t ws_size,
                              hipStream_t stream) {
    const float* X  = (const float*)d_in[0];
    const float* Wf = (const float*)d_in[1];
    const float* bf = (const float*)d_in[2];
    const float* Wi = (const float*)d_in[3];
    const float* bi = (const float*)d_in[4];
    const float* Wg = (const float*)d_in[5];
    const float* bg = (const float*)d_in[6];
    const float* Wo = (const float*)d_in[7];
    const float* bo = (const float*)d_in[8];
    float* out = (float*)d_out;

    qlstm_fused<<<BATCH / 2, 512, 0, stream>>>(
        X, Wf, bf, Wi, bi, Wg, bg, Wo, bo, out);
}